// Round 2
// baseline (1013.756 us; speedup 1.0000x reference)
//
#include <hip/hip_runtime.h>
#include <math.h>

#define NN 100000
#define NE 1600000
#define DD 32
#define CC 16

typedef unsigned short bf16_t;
struct us4 { bf16_t x, y, z, w; };

static inline unsigned gblocks(long total) { return (unsigned)((total + 255) / 256); }

__device__ inline bf16_t f2bf(float f) {
    unsigned u = __float_as_uint(f);
    u += 0x7fffu + ((u >> 16) & 1u);
    return (bf16_t)(u >> 16);
}
__device__ inline float bf2f(bf16_t h) { return __uint_as_float(((unsigned)h) << 16); }

__global__ void zero_k(float* p, long n) {
    long i = (long)blockIdx.x * 256 + threadIdx.x;
    if (i < n) p[i] = 0.f;
}

__global__ void count_k(const int* __restrict__ dst, float* __restrict__ cnt) {
    int e = blockIdx.x * 256 + threadIdx.x;
    if (e < NE) atomicAdd(&cnt[dst[e]], 1.0f);
}

// y[n,k,:] = x[n,:] @ W[k]; one thread computes 4 consecutive output dims
template<int K, bool BF>
__global__ void y_k(const float* __restrict__ x, const float* __restrict__ W,
                    void* __restrict__ yv) {
    long tid = (long)blockIdx.x * 256 + threadIdx.x;
    const long total = (long)NN * K * 8;
    if (tid >= total) return;
    int eq = (int)(tid & 7);
    long nk = tid >> 3;
    int k = (int)(nk % K);
    long n = nk / K;
    const float* xr = x + n * DD;
    const float4* Wk = (const float4*)(W + (long)k * DD * DD) + eq;
    float4 acc = make_float4(0.f, 0.f, 0.f, 0.f);
#pragma unroll
    for (int d = 0; d < DD; ++d) {
        float xv = xr[d];
        float4 w = Wk[(long)d * 8];
        acc.x = fmaf(xv, w.x, acc.x);
        acc.y = fmaf(xv, w.y, acc.y);
        acc.z = fmaf(xv, w.z, acc.z);
        acc.w = fmaf(xv, w.w, acc.w);
    }
    if (BF) {
        us4 o; o.x = f2bf(acc.x); o.y = f2bf(acc.y); o.z = f2bf(acc.z); o.w = f2bf(acc.w);
        ((us4*)yv)[tid] = o;
    } else {
        ((float4*)yv)[tid] = acc;
    }
}

// per (edge, e): 4-tap bilinear blend of gathered y rows, atomic scatter
template<int KS, bool BF>
__global__ void edge_y_k(const int* __restrict__ src, const int* __restrict__ dst,
                         const float* __restrict__ attr, const void* __restrict__ yv,
                         float* __restrict__ agg) {
    long tid = (long)blockIdx.x * 256 + threadIdx.x;
    if (tid >= (long)NE * DD) return;
    int e = (int)(tid & (DD - 1));
    int ed = (int)(tid >> 5);
    const int K = KS * KS;
    float u0 = attr[2 * ed], u1 = attr[2 * ed + 1];
    float v0 = u0 * (KS - 1), v1 = u1 * (KS - 1);
    float fb0 = floorf(v0), fb1 = floorf(v1);
    float f0 = v0 - fb0, f1 = v1 - fb1;
    int i0 = min((int)fb0, KS - 1), i1 = min((int)fb1, KS - 1);
    int j0 = min(i0 + 1, KS - 1), j1 = min(i1 + 1, KS - 1);
    int s = src[ed];
    long base = (long)s * K * DD + e;
    float y00, y10, y01, y11;
    if (BF) {
        const bf16_t* y = (const bf16_t*)yv;
        y00 = bf2f(y[base + (i0 + i1 * KS) * DD]);
        y10 = bf2f(y[base + (j0 + i1 * KS) * DD]);
        y01 = bf2f(y[base + (i0 + j1 * KS) * DD]);
        y11 = bf2f(y[base + (j0 + j1 * KS) * DD]);
    } else {
        const float* y = (const float*)yv;
        y00 = y[base + (i0 + i1 * KS) * DD];
        y10 = y[base + (j0 + i1 * KS) * DD];
        y01 = y[base + (i0 + j1 * KS) * DD];
        y11 = y[base + (j0 + j1 * KS) * DD];
    }
    float m = (1.f - f0) * (1.f - f1) * y00 + f0 * (1.f - f1) * y10
            + (1.f - f0) * f1 * y01 + f0 * f1 * y11;
    atomicAdd(&agg[(long)dst[ed] * DD + e], m);
}

// no-workspace fallback: per-edge direct compute, W staged in LDS
template<int KS>
__global__ __launch_bounds__(1024) void edge_direct_k(
        const int* __restrict__ src, const int* __restrict__ dst,
        const float* __restrict__ attr, const float* __restrict__ x,
        const float* __restrict__ W, float* __restrict__ agg) {
    const int K = KS * KS;
    __shared__ float Wl[K * DD * DD];
    for (int i = threadIdx.x; i < K * DD * DD; i += 1024) Wl[i] = W[i];
    __syncthreads();
    int lane = threadIdx.x & 31;
    int eg = threadIdx.x >> 5;  // 32 edges per block-iteration
    for (int ed = blockIdx.x * 32 + eg; ed < NE; ed += gridDim.x * 32) {
        float u0 = attr[2 * ed], u1 = attr[2 * ed + 1];
        float v0 = u0 * (KS - 1), v1 = u1 * (KS - 1);
        float fb0 = floorf(v0), fb1 = floorf(v1);
        float f0 = v0 - fb0, f1 = v1 - fb1;
        int i0 = min((int)fb0, KS - 1), i1 = min((int)fb1, KS - 1);
        int j0 = min(i0 + 1, KS - 1), j1 = min(i1 + 1, KS - 1);
        int s = src[ed];
        float xv = x[(long)s * DD + lane];
        const float* W00 = &Wl[(i0 + i1 * KS) * DD * DD + lane];
        const float* W10 = &Wl[(j0 + i1 * KS) * DD * DD + lane];
        const float* W01 = &Wl[(i0 + j1 * KS) * DD * DD + lane];
        const float* W11 = &Wl[(j0 + j1 * KS) * DD * DD + lane];
        float a00 = 0.f, a10 = 0.f, a01 = 0.f, a11 = 0.f;
#pragma unroll
        for (int d = 0; d < DD; ++d) {
            float xd = __shfl(xv, d, 32);
            a00 = fmaf(xd, W00[d * DD], a00);
            a10 = fmaf(xd, W10[d * DD], a10);
            a01 = fmaf(xd, W01[d * DD], a01);
            a11 = fmaf(xd, W11[d * DD], a11);
        }
        float m = (1.f - f0) * (1.f - f1) * a00 + f0 * (1.f - f1) * a10
                + (1.f - f0) * f1 * a01 + f0 * f1 * a11;
        atomicAdd(&agg[(long)dst[ed] * DD + lane], m);
    }
}

// h[n,e] = elu(agg[n,e]/max(cnt,1) + x[n,:]@root[:,e] + bias[e])
__global__ void fin_k(const float* __restrict__ agg, const float* __restrict__ cnt,
                      const float* x, const float* __restrict__ root,
                      const float* __restrict__ bias, float* h) {
    long tid = (long)blockIdx.x * 256 + threadIdx.x;
    if (tid >= (long)NN * DD) return;
    int e = (int)(tid & (DD - 1));
    long n = tid >> 5;
    float c = cnt[n]; if (c < 1.f) c = 1.f;
    const float* xr = x + n * DD;
    float acc = 0.f;
#pragma unroll
    for (int d = 0; d < DD; ++d) acc = fmaf(xr[d], root[d * DD + e], acc);
    float v = agg[tid] / c + acc + bias[e];
    h[tid] = v > 0.f ? v : expm1f(v);
}

__global__ void mlp1_k(const float* __restrict__ h, const float* __restrict__ w,
                       const float* __restrict__ b, float* __restrict__ t) {
    long tid = (long)blockIdx.x * 256 + threadIdx.x;
    if (tid >= (long)NN * DD) return;
    int e = (int)(tid & (DD - 1));
    long n = tid >> 5;
    const float* hr = h + n * DD;
    float acc = 0.f;
#pragma unroll
    for (int d = 0; d < DD; ++d) acc = fmaf(hr[d], w[d * DD + e], acc);
    acc += b[e];
    t[tid] = fmaxf(acc, 0.f);
}

__global__ void mlp2_k(const float* __restrict__ t, const float* __restrict__ w,
                       const float* __restrict__ b, float* __restrict__ out) {
    long tid = (long)blockIdx.x * 256 + threadIdx.x;
    if (tid >= (long)NN * CC) return;
    int c = (int)(tid & (CC - 1));
    long n = tid >> 4;
    const float* tr = t + n * DD;
    float acc = 0.f;
#pragma unroll
    for (int d = 0; d < DD; ++d) acc = fmaf(tr[d], w[d * CC + c], acc);
    acc += b[c];
    out[tid] = fmaxf(acc, 0.f);
}

extern "C" void kernel_launch(void* const* d_in, const int* in_sizes, int n_in,
                              void* d_out, int out_size, void* d_ws, size_t ws_size,
                              hipStream_t stream) {
    const float* x     = (const float*)d_in[0];
    const int*   ei    = (const int*)d_in[1];
    const float* attr  = (const float*)d_in[2];
    const float* W1    = (const float*)d_in[3];
    const float* root1 = (const float*)d_in[4];
    const float* bias1 = (const float*)d_in[5];
    const float* W2    = (const float*)d_in[6];
    const float* root2 = (const float*)d_in[7];
    const float* bias2 = (const float*)d_in[8];
    const float* m1w   = (const float*)d_in[9];
    const float* m1b   = (const float*)d_in[10];
    const float* m2w   = (const float*)d_in[11];
    const float* m2b   = (const float*)d_in[12];
    float* out = (float*)d_out;

    const int* srcp = ei;
    const int* dstp = ei + NE;

    // common workspace: agg | cnt | h1 | h2 | [y]
    float* agg = (float*)d_ws;
    float* cnt = agg + (size_t)NN * DD;
    float* h1  = cnt + NN;
    float* h2  = h1 + (size_t)NN * DD;
    void*  yv  = (void*)(h2 + (size_t)NN * DD);
    float* t1  = agg;  // reused after layer-2 finalize

    const size_t commonf = (size_t)NN * DD * 3 + NN;          // 9.7M floats
    const size_t yelems  = (size_t)NN * 25 * DD;              // 80M
    const size_t need32  = (commonf + yelems) * 4;            // ~358.8 MB
    const size_t need16  = commonf * 4 + yelems * 2;          // ~198.8 MB
    int mode = (ws_size >= need32) ? 2 : (ws_size >= need16) ? 1 : 0;

    zero_k<<<gblocks((long)NN * DD + NN), 256, 0, stream>>>(agg, (long)NN * DD + NN);
    count_k<<<gblocks(NE), 256, 0, stream>>>(dstp, cnt);

    // ---- layer 1 (ksize=3, K=9) ----
    if (mode == 2) {
        y_k<9, false><<<gblocks((long)NN * 9 * 8), 256, 0, stream>>>(x, W1, yv);
        edge_y_k<3, false><<<gblocks((long)NE * DD), 256, 0, stream>>>(srcp, dstp, attr, yv, agg);
    } else if (mode == 1) {
        y_k<9, true><<<gblocks((long)NN * 9 * 8), 256, 0, stream>>>(x, W1, yv);
        edge_y_k<3, true><<<gblocks((long)NE * DD), 256, 0, stream>>>(srcp, dstp, attr, yv, agg);
    } else {
        edge_direct_k<3><<<512, 1024, 0, stream>>>(srcp, dstp, attr, x, W1, agg);
    }
    fin_k<<<gblocks((long)NN * DD), 256, 0, stream>>>(agg, cnt, x, root1, bias1, h1);

    // ---- layer 2 (ksize=5, K=25) ----
    zero_k<<<gblocks((long)NN * DD), 256, 0, stream>>>(agg, (long)NN * DD);
    if (mode == 2) {
        y_k<25, false><<<gblocks((long)NN * 25 * 8), 256, 0, stream>>>(h1, W2, yv);
        edge_y_k<5, false><<<gblocks((long)NE * DD), 256, 0, stream>>>(srcp, dstp, attr, yv, agg);
    } else if (mode == 1) {
        y_k<25, true><<<gblocks((long)NN * 25 * 8), 256, 0, stream>>>(h1, W2, yv);
        edge_y_k<5, true><<<gblocks((long)NE * DD), 256, 0, stream>>>(srcp, dstp, attr, yv, agg);
    } else {
        edge_direct_k<5><<<256, 1024, 0, stream>>>(srcp, dstp, attr, h1, W2, agg);
    }
    fin_k<<<gblocks((long)NN * DD), 256, 0, stream>>>(agg, cnt, h1, root2, bias2, h2);

    // ---- MLP head ----
    mlp1_k<<<gblocks((long)NN * DD), 256, 0, stream>>>(h2, m1w, m1b, t1);
    mlp2_k<<<gblocks((long)NN * CC), 256, 0, stream>>>(t1, m2w, m2b, out);
}

// Round 3
// 905.257 us; speedup vs baseline: 1.1199x; 1.1199x over previous
//
#include <hip/hip_runtime.h>
#include <math.h>

#define NN 100000
#define NE 1600000
#define DD 32
#define CC 16

typedef unsigned short bf16_t;
struct us4 { bf16_t x, y, z, w; };

static inline unsigned gblocks(long total) { return (unsigned)((total + 255) / 256); }

__device__ inline bf16_t f2bf(float f) {
    unsigned u = __float_as_uint(f);
    u += 0x7fffu + ((u >> 16) & 1u);
    return (bf16_t)(u >> 16);
}
__device__ inline float bf2f(bf16_t h) { return __uint_as_float(((unsigned)h) << 16); }

__global__ void zero_k(float* p, long n) {
    long i = (long)blockIdx.x * 256 + threadIdx.x;
    if (i < n) p[i] = 0.f;
}

__global__ void count_k(const int* __restrict__ dst, float* __restrict__ cnt) {
    int e = blockIdx.x * 256 + threadIdx.x;
    if (e < NE) atomicAdd(&cnt[dst[e]], 1.0f);
}

// y[n,k,:] = x[n,:] @ W[k].  Tiled: block = 128-node tile x one k.
// x tile staged in LDS (stride 36: float4-aligned + conflict-free);
// W[k] (4KB) streams via L1, each float4 reused across 4 nodes in regs.
template<int K, bool BF>
__global__ __launch_bounds__(256) void y2_k(const float* __restrict__ x,
                                            const float* __restrict__ W,
                                            void* __restrict__ yv) {
    __shared__ float xs[128 * 36];
    const int k = blockIdx.y;
    const long n0 = (long)blockIdx.x * 128;
    const int tid = threadIdx.x;

    // cooperative load: 128 rows x 8 float4 = 1024 float4
#pragma unroll
    for (int i = 0; i < 4; ++i) {
        int idx = tid + 256 * i;
        int row = idx >> 3;
        int c4 = idx & 7;
        long n = n0 + row;
        float4 v = make_float4(0.f, 0.f, 0.f, 0.f);
        if (n < NN) v = ((const float4*)x)[n * 8 + c4];
        *(float4*)&xs[row * 36 + c4 * 4] = v;
    }
    __syncthreads();

    const int eq = tid & 7;        // output dim quad
    const int nl = tid >> 3;       // node lane 0..31
    const float4* Wk = (const float4*)(W + (long)k * DD * DD) + eq;

    float4 a0 = make_float4(0, 0, 0, 0), a1 = a0, a2 = a0, a3 = a0;
#pragma unroll
    for (int d4 = 0; d4 < 8; ++d4) {
        float4 w0 = Wk[(4 * d4 + 0) * 8];
        float4 w1 = Wk[(4 * d4 + 1) * 8];
        float4 w2 = Wk[(4 * d4 + 2) * 8];
        float4 w3 = Wk[(4 * d4 + 3) * 8];
#pragma unroll
        for (int j = 0; j < 4; ++j) {
            float4 xv = *(const float4*)&xs[(nl + 32 * j) * 36 + d4 * 4];
            float4& a = j == 0 ? a0 : j == 1 ? a1 : j == 2 ? a2 : a3;
            a.x = fmaf(xv.x, w0.x, a.x); a.y = fmaf(xv.x, w0.y, a.y);
            a.z = fmaf(xv.x, w0.z, a.z); a.w = fmaf(xv.x, w0.w, a.w);
            a.x = fmaf(xv.y, w1.x, a.x); a.y = fmaf(xv.y, w1.y, a.y);
            a.z = fmaf(xv.y, w1.z, a.z); a.w = fmaf(xv.y, w1.w, a.w);
            a.x = fmaf(xv.z, w2.x, a.x); a.y = fmaf(xv.z, w2.y, a.y);
            a.z = fmaf(xv.z, w2.z, a.z); a.w = fmaf(xv.z, w2.w, a.w);
            a.x = fmaf(xv.w, w3.x, a.x); a.y = fmaf(xv.w, w3.y, a.y);
            a.z = fmaf(xv.w, w3.z, a.z); a.w = fmaf(xv.w, w3.w, a.w);
        }
    }

#pragma unroll
    for (int j = 0; j < 4; ++j) {
        long n = n0 + nl + 32 * j;
        if (n >= NN) continue;
        float4 a = j == 0 ? a0 : j == 1 ? a1 : j == 2 ? a2 : a3;
        long oidx = (n * K + k) * 8 + eq;
        if (BF) {
            us4 o; o.x = f2bf(a.x); o.y = f2bf(a.y); o.z = f2bf(a.z); o.w = f2bf(a.w);
            ((us4*)yv)[oidx] = o;
        } else {
            ((float4*)yv)[oidx] = a;
        }
    }
}

// per (edge, e): 4-tap bilinear blend of gathered y rows, atomic scatter
template<int KS, bool BF>
__global__ void edge_y_k(const int* __restrict__ src, const int* __restrict__ dst,
                         const float* __restrict__ attr, const void* __restrict__ yv,
                         float* __restrict__ agg) {
    long tid = (long)blockIdx.x * 256 + threadIdx.x;
    if (tid >= (long)NE * DD) return;
    int e = (int)(tid & (DD - 1));
    int ed = (int)(tid >> 5);
    const int K = KS * KS;
    float u0 = attr[2 * ed], u1 = attr[2 * ed + 1];
    float v0 = u0 * (KS - 1), v1 = u1 * (KS - 1);
    float fb0 = floorf(v0), fb1 = floorf(v1);
    float f0 = v0 - fb0, f1 = v1 - fb1;
    int i0 = min((int)fb0, KS - 1), i1 = min((int)fb1, KS - 1);
    int j0 = min(i0 + 1, KS - 1), j1 = min(i1 + 1, KS - 1);
    int s = src[ed];
    long base = (long)s * K * DD + e;
    float y00, y10, y01, y11;
    if (BF) {
        const bf16_t* y = (const bf16_t*)yv;
        y00 = bf2f(y[base + (i0 + i1 * KS) * DD]);
        y10 = bf2f(y[base + (j0 + i1 * KS) * DD]);
        y01 = bf2f(y[base + (i0 + j1 * KS) * DD]);
        y11 = bf2f(y[base + (j0 + j1 * KS) * DD]);
    } else {
        const float* y = (const float*)yv;
        y00 = y[base + (i0 + i1 * KS) * DD];
        y10 = y[base + (j0 + i1 * KS) * DD];
        y01 = y[base + (i0 + j1 * KS) * DD];
        y11 = y[base + (j0 + j1 * KS) * DD];
    }
    float m = (1.f - f0) * (1.f - f1) * y00 + f0 * (1.f - f1) * y10
            + (1.f - f0) * f1 * y01 + f0 * f1 * y11;
    atomicAdd(&agg[(long)dst[ed] * DD + e], m);
}

// no-workspace fallback: per-edge direct compute, W staged in LDS
template<int KS>
__global__ __launch_bounds__(1024) void edge_direct_k(
        const int* __restrict__ src, const int* __restrict__ dst,
        const float* __restrict__ attr, const float* __restrict__ x,
        const float* __restrict__ W, float* __restrict__ agg) {
    const int K = KS * KS;
    __shared__ float Wl[K * DD * DD];
    for (int i = threadIdx.x; i < K * DD * DD; i += 1024) Wl[i] = W[i];
    __syncthreads();
    int lane = threadIdx.x & 31;
    int eg = threadIdx.x >> 5;
    for (int ed = blockIdx.x * 32 + eg; ed < NE; ed += gridDim.x * 32) {
        float u0 = attr[2 * ed], u1 = attr[2 * ed + 1];
        float v0 = u0 * (KS - 1), v1 = u1 * (KS - 1);
        float fb0 = floorf(v0), fb1 = floorf(v1);
        float f0 = v0 - fb0, f1 = v1 - fb1;
        int i0 = min((int)fb0, KS - 1), i1 = min((int)fb1, KS - 1);
        int j0 = min(i0 + 1, KS - 1), j1 = min(i1 + 1, KS - 1);
        int s = src[ed];
        float xv = x[(long)s * DD + lane];
        const float* W00 = &Wl[(i0 + i1 * KS) * DD * DD + lane];
        const float* W10 = &Wl[(j0 + i1 * KS) * DD * DD + lane];
        const float* W01 = &Wl[(i0 + j1 * KS) * DD * DD + lane];
        const float* W11 = &Wl[(j0 + j1 * KS) * DD * DD + lane];
        float a00 = 0.f, a10 = 0.f, a01 = 0.f, a11 = 0.f;
#pragma unroll
        for (int d = 0; d < DD; ++d) {
            float xd = __shfl(xv, d, 32);
            a00 = fmaf(xd, W00[d * DD], a00);
            a10 = fmaf(xd, W10[d * DD], a10);
            a01 = fmaf(xd, W01[d * DD], a01);
            a11 = fmaf(xd, W11[d * DD], a11);
        }
        float m = (1.f - f0) * (1.f - f1) * a00 + f0 * (1.f - f1) * a10
                + (1.f - f0) * f1 * a01 + f0 * f1 * a11;
        atomicAdd(&agg[(long)dst[ed] * DD + lane], m);
    }
}

__global__ void fin_k(const float* __restrict__ agg, const float* __restrict__ cnt,
                      const float* x, const float* __restrict__ root,
                      const float* __restrict__ bias, float* h) {
    long tid = (long)blockIdx.x * 256 + threadIdx.x;
    if (tid >= (long)NN * DD) return;
    int e = (int)(tid & (DD - 1));
    long n = tid >> 5;
    float c = cnt[n]; if (c < 1.f) c = 1.f;
    const float* xr = x + n * DD;
    float acc = 0.f;
#pragma unroll
    for (int d = 0; d < DD; ++d) acc = fmaf(xr[d], root[d * DD + e], acc);
    float v = agg[tid] / c + acc + bias[e];
    h[tid] = v > 0.f ? v : expm1f(v);
}

__global__ void mlp1_k(const float* __restrict__ h, const float* __restrict__ w,
                       const float* __restrict__ b, float* __restrict__ t) {
    long tid = (long)blockIdx.x * 256 + threadIdx.x;
    if (tid >= (long)NN * DD) return;
    int e = (int)(tid & (DD - 1));
    long n = tid >> 5;
    const float* hr = h + n * DD;
    float acc = 0.f;
#pragma unroll
    for (int d = 0; d < DD; ++d) acc = fmaf(hr[d], w[d * DD + e], acc);
    acc += b[e];
    t[tid] = fmaxf(acc, 0.f);
}

__global__ void mlp2_k(const float* __restrict__ t, const float* __restrict__ w,
                       const float* __restrict__ b, float* __restrict__ out) {
    long tid = (long)blockIdx.x * 256 + threadIdx.x;
    if (tid >= (long)NN * CC) return;
    int c = (int)(tid & (CC - 1));
    long n = tid >> 4;
    const float* tr = t + n * DD;
    float acc = 0.f;
#pragma unroll
    for (int d = 0; d < DD; ++d) acc = fmaf(tr[d], w[d * CC + c], acc);
    acc += b[c];
    out[tid] = fmaxf(acc, 0.f);
}

extern "C" void kernel_launch(void* const* d_in, const int* in_sizes, int n_in,
                              void* d_out, int out_size, void* d_ws, size_t ws_size,
                              hipStream_t stream) {
    const float* x     = (const float*)d_in[0];
    const int*   ei    = (const int*)d_in[1];
    const float* attr  = (const float*)d_in[2];
    const float* W1    = (const float*)d_in[3];
    const float* root1 = (const float*)d_in[4];
    const float* bias1 = (const float*)d_in[5];
    const float* W2    = (const float*)d_in[6];
    const float* root2 = (const float*)d_in[7];
    const float* bias2 = (const float*)d_in[8];
    const float* m1w   = (const float*)d_in[9];
    const float* m1b   = (const float*)d_in[10];
    const float* m2w   = (const float*)d_in[11];
    const float* m2b   = (const float*)d_in[12];
    float* out = (float*)d_out;

    const int* srcp = ei;
    const int* dstp = ei + NE;

    float* agg = (float*)d_ws;
    float* cnt = agg + (size_t)NN * DD;
    float* h1  = cnt + NN;
    float* h2  = h1 + (size_t)NN * DD;
    void*  yv  = (void*)(h2 + (size_t)NN * DD);
    float* t1  = agg;

    const size_t commonf = (size_t)NN * DD * 3 + NN;
    const size_t yelems  = (size_t)NN * 25 * DD;
    const size_t need32  = (commonf + yelems) * 4;
    const size_t need16  = commonf * 4 + yelems * 2;
    int mode = (ws_size >= need32) ? 2 : (ws_size >= need16) ? 1 : 0;

    const unsigned gy = (NN + 127) / 128;

    zero_k<<<gblocks((long)NN * DD + NN), 256, 0, stream>>>(agg, (long)NN * DD + NN);
    count_k<<<gblocks(NE), 256, 0, stream>>>(dstp, cnt);

    // ---- layer 1 (ksize=3, K=9) ----
    if (mode == 2) {
        y2_k<9, false><<<dim3(gy, 9), 256, 0, stream>>>(x, W1, yv);
        edge_y_k<3, false><<<gblocks((long)NE * DD), 256, 0, stream>>>(srcp, dstp, attr, yv, agg);
    } else if (mode == 1) {
        y2_k<9, true><<<dim3(gy, 9), 256, 0, stream>>>(x, W1, yv);
        edge_y_k<3, true><<<gblocks((long)NE * DD), 256, 0, stream>>>(srcp, dstp, attr, yv, agg);
    } else {
        edge_direct_k<3><<<512, 1024, 0, stream>>>(srcp, dstp, attr, x, W1, agg);
    }
    fin_k<<<gblocks((long)NN * DD), 256, 0, stream>>>(agg, cnt, x, root1, bias1, h1);

    // ---- layer 2 (ksize=5, K=25) ----
    zero_k<<<gblocks((long)NN * DD), 256, 0, stream>>>(agg, (long)NN * DD);
    if (mode == 2) {
        y2_k<25, false><<<dim3(gy, 25), 256, 0, stream>>>(h1, W2, yv);
        edge_y_k<5, false><<<gblocks((long)NE * DD), 256, 0, stream>>>(srcp, dstp, attr, yv, agg);
    } else if (mode == 1) {
        y2_k<25, true><<<dim3(gy, 25), 256, 0, stream>>>(h1, W2, yv);
        edge_y_k<5, true><<<gblocks((long)NE * DD), 256, 0, stream>>>(srcp, dstp, attr, yv, agg);
    } else {
        edge_direct_k<5><<<256, 1024, 0, stream>>>(srcp, dstp, attr, h1, W2, agg);
    }
    fin_k<<<gblocks((long)NN * DD), 256, 0, stream>>>(agg, cnt, h1, root2, bias2, h2);

    // ---- MLP head ----
    mlp1_k<<<gblocks((long)NN * DD), 256, 0, stream>>>(h2, m1w, m1b, t1);
    mlp2_k<<<gblocks((long)NN * CC), 256, 0, stream>>>(t1, m2w, m2b, out);
}